// Round 4
// baseline (140.503 us; speedup 1.0000x reference)
//
#include <hip/hip_runtime.h>

// StableContrastiveLoss on MI355X (gfx950).  B=4096, D=512, C=10, T=0.07.
// Round 4: NO-LDS sim kernel. K=512 is too short for staged pipelines
// (R2/R3 post-mortem: barrier-latency-bound at 2 blk/CU, MfmaUtil 3.6%).
// Fragments load directly from global (L2-resident F, 4 MB): per 32-col
// K-step = 8x global_load_dwordx4 + 16 MFMA, zero barriers, zero LDS staging.
// Symmetric upper-triangle 128x128 tiles; finalize fused via ticket.
// ws: F_bf16 [4096*512] | cls [4096] | pos_sum [4096] | all_sum [4096] | done

#define B_ROWS 4096
#define D_DIM  512
#define C_CLS  10
#define NT     32                     // 4096/128 tile-blocks per dim
#define NTILES (NT * (NT + 1) / 2)    // 528 upper-triangle tiles

typedef __bf16 bf16x8 __attribute__((ext_vector_type(8)));
typedef float  f32x4  __attribute__((ext_vector_type(4)));

// ---------------- Kernel 1: normalize rows + class extract + zero accum ----
__global__ __launch_bounds__(256) void prep_kernel(
    const float* __restrict__ feats, const float* __restrict__ labels,
    __bf16* __restrict__ F, int* __restrict__ cls,
    float* __restrict__ pos_sum, float* __restrict__ all_sum,
    int* __restrict__ done) {
  const int w = threadIdx.x >> 6, lane = threadIdx.x & 63;
  const int row = blockIdx.x * 4 + w;   // one wave per row
  const float* fr = feats + (size_t)row * D_DIM;
  float4 v0 = ((const float4*)fr)[2 * lane];
  float4 v1 = ((const float4*)fr)[2 * lane + 1];
  float ss = v0.x*v0.x + v0.y*v0.y + v0.z*v0.z + v0.w*v0.w
           + v1.x*v1.x + v1.y*v1.y + v1.z*v1.z + v1.w*v1.w;
  #pragma unroll
  for (int m = 1; m < 64; m <<= 1) ss += __shfl_xor(ss, m, 64);
  float inv = 1.0f / sqrtf(ss);

  bf16x8 o;
  o[0] = (__bf16)(v0.x * inv); o[1] = (__bf16)(v0.y * inv);
  o[2] = (__bf16)(v0.z * inv); o[3] = (__bf16)(v0.w * inv);
  o[4] = (__bf16)(v1.x * inv); o[5] = (__bf16)(v1.y * inv);
  o[6] = (__bf16)(v1.z * inv); o[7] = (__bf16)(v1.w * inv);
  *(bf16x8*)(F + (size_t)row * D_DIM + 8 * lane) = o;

  float lv = (lane < C_CLS) ? labels[(size_t)row * C_CLS + lane] : 0.f;
  unsigned long long m = __ballot(lv > 0.5f);
  if (lane == 0) {
    cls[row] = (int)(__ffsll((long long)m) - 1);
    pos_sum[row] = 0.f;
    all_sum[row] = 0.f;
  }
  if (blockIdx.x == 0 && threadIdx.x == 0) *done = 0;
}

// ------- Kernel 2: barrier-free symmetric sim + exp + sums + finalize ------
__global__ __launch_bounds__(256, 2) void sim_kernel(
    const __bf16* __restrict__ F, const int* __restrict__ cls,
    float* __restrict__ pos_sum, float* __restrict__ all_sum,
    int* __restrict__ done, float* __restrict__ out) {
  __shared__ int clsA[128], clsB[128];
  __shared__ int ticket_s;
  __shared__ float redv[8];

  // triangular tile decode (block-uniform, <=32 scalar iters)
  int rem = blockIdx.x, bi = 0, rowlen = NT;
  while (rem >= rowlen) { rem -= rowlen; ++bi; --rowlen; }
  const int bj = bi + rem;
  const int i0 = bi * 128, j0 = bj * 128;
  const bool offdiag = (bi != bj);

  const int tid = threadIdx.x;
  const int w = tid >> 6, lane = tid & 63;
  const int wi = w & 1, wj = w >> 1;       // 2x2 wave grid over 128x128
  const int q = lane >> 4, cl = lane & 15;

  if (tid < 128) clsA[tid] = cls[i0 + tid];
  else           clsB[tid - 128] = cls[j0 + tid - 128];
  __syncthreads();   // the only barrier: clsA/B visible for the epilogue

  f32x4 acc[4][4];
  #pragma unroll
  for (int ri = 0; ri < 4; ++ri)
    #pragma unroll
    for (int cj = 0; cj < 4; ++cj) acc[ri][cj] = (f32x4){0.f, 0.f, 0.f, 0.f};

  // Fragment base pointers. A-operand layout (m89/m91): m = lane&15,
  // k = (lane>>4)*8 + j. NT symmetry: B fragment = same pattern on rows j.
  // All 16 K-step offsets (k0*2 bytes, <= 960) fit the 13-bit immediate:
  // the K-loop body is pure loads + MFMAs.
  const __bf16* pa[4];
  const __bf16* pb[4];
  #pragma unroll
  for (int ri = 0; ri < 4; ++ri) {
    pa[ri] = F + (size_t)(i0 + 64 * wi + 16 * ri + cl) * D_DIM + q * 8;
    pb[ri] = F + (size_t)(j0 + 64 * wj + 16 * ri + cl) * D_DIM + q * 8;
  }

  #pragma unroll 2
  for (int k0 = 0; k0 < D_DIM; k0 += 32) {
    bf16x8 af[4], bb[4];
    #pragma unroll
    for (int ri = 0; ri < 4; ++ri) af[ri] = *(const bf16x8*)(pa[ri] + k0);
    #pragma unroll
    for (int cj = 0; cj < 4; ++cj) bb[cj] = *(const bf16x8*)(pb[cj] + k0);
    #pragma unroll
    for (int ri = 0; ri < 4; ++ri)
      #pragma unroll
      for (int cj = 0; cj < 4; ++cj)
        acc[ri][cj] = __builtin_amdgcn_mfma_f32_16x16x32_bf16(
            af[ri], bb[cj], acc[ri][cj], 0, 0, 0);
  }

  // Epilogue. D layout: col = lane&15 (j), row = q*4 + reg (i).
  const float invT = 1.0f / 0.07f;
  float cs_all[4] = {0.f, 0.f, 0.f, 0.f};
  float cs_pos[4] = {0.f, 0.f, 0.f, 0.f};

  #pragma unroll
  for (int ri = 0; ri < 4; ++ri) {
    float ra[4] = {0.f, 0.f, 0.f, 0.f};
    float rp[4] = {0.f, 0.f, 0.f, 0.f};
    #pragma unroll
    for (int cj = 0; cj < 4; ++cj) {
      const int jloc = 64 * wj + 16 * cj + cl;
      const int gj = j0 + jloc;
      const int cjc = clsB[jloc];
      #pragma unroll
      for (int r = 0; r < 4; ++r) {
        const int iloc = 64 * wi + 16 * ri + q * 4 + r;
        const int gi = i0 + iloc;
        float s = acc[ri][cj][r] * invT;
        s = fminf(fmaxf(s, -20.f), 20.f);
        const bool diag = (gi == gj);
        float e = diag ? 0.f : __expf(s);
        ra[r] += e;
        cs_all[cj] += e;
        if (!diag && cjc == clsA[iloc]) { rp[r] += e; cs_pos[cj] += e; }
      }
    }
    #pragma unroll
    for (int r = 0; r < 4; ++r) {
      float sa = ra[r], sp = rp[r];
      #pragma unroll
      for (int m = 1; m < 16; m <<= 1) {
        sa += __shfl_xor(sa, m, 64);
        sp += __shfl_xor(sp, m, 64);
      }
      if (cl == 0) {
        const int gi = i0 + 64 * wi + 16 * ri + q * 4 + r;
        atomicAdd(&all_sum[gi], sa);
        atomicAdd(&pos_sum[gi], sp);
      }
    }
  }
  if (offdiag) {   // symmetry: column sums feed rows j
    #pragma unroll
    for (int cj = 0; cj < 4; ++cj) {
      float sa = cs_all[cj], sp = cs_pos[cj];
      sa += __shfl_xor(sa, 16, 64); sa += __shfl_xor(sa, 32, 64);
      sp += __shfl_xor(sp, 16, 64); sp += __shfl_xor(sp, 32, 64);
      if (q == 0) {
        const int gj = j0 + 64 * wj + 16 * cj + cl;
        atomicAdd(&all_sum[gj], sa);
        atomicAdd(&pos_sum[gj], sp);
      }
    }
  }

  // ---- fused finalize: last block to finish reduces the loss ----
  __threadfence();           // release our atomics before taking a ticket
  __syncthreads();
  if (tid == 0) ticket_s = atomicAdd(done, 1);
  __syncthreads();
  if (ticket_s == NTILES - 1) {   // block-uniform
    __threadfence();         // acquire all other blocks' sums
    float total = 0.f, cnt = 0.f;
    for (int i = tid; i < B_ROWS; i += 256) {
      float ps = pos_sum[i], as = all_sum[i];
      if (ps > 0.f) {        // valid iff >=1 positive (exp > 0 always)
        total += -__logf(ps / (as + 1e-8f) + 1e-8f);
        cnt += 1.f;
      }
    }
    #pragma unroll
    for (int m = 1; m < 64; m <<= 1) {
      total += __shfl_xor(total, m, 64);
      cnt   += __shfl_xor(cnt, m, 64);
    }
    if ((tid & 63) == 0) { redv[tid >> 6] = total; redv[4 + (tid >> 6)] = cnt; }
    __syncthreads();
    if (tid == 0) {
      float T = 0.f, Cn = 0.f;
      #pragma unroll
      for (int i = 0; i < 4; ++i) { T += redv[i]; Cn += redv[4 + i]; }
      out[0] = (Cn > 0.f) ? (T / Cn) : 0.f;
    }
  }
}

extern "C" void kernel_launch(void* const* d_in, const int* in_sizes, int n_in,
                              void* d_out, int out_size, void* d_ws, size_t ws_size,
                              hipStream_t stream) {
  const float* features = (const float*)d_in[0];
  const float* labels   = (const float*)d_in[1];
  float* out = (float*)d_out;

  __bf16* F       = (__bf16*)d_ws;
  int*    cls     = (int*)((char*)d_ws + (size_t)B_ROWS * D_DIM * 2);
  float*  pos_sum = (float*)((char*)cls + B_ROWS * sizeof(int));
  float*  all_sum = pos_sum + B_ROWS;
  int*    done    = (int*)(all_sum + B_ROWS);

  prep_kernel<<<B_ROWS / 4, 256, 0, stream>>>(features, labels, F, cls,
                                              pos_sum, all_sum, done);
  sim_kernel<<<NTILES, 256, 0, stream>>>(F, cls, pos_sum, all_sum, done, out);
}

// Round 5
// 102.814 us; speedup vs baseline: 1.3666x; 1.3666x over previous
//
#include <hip/hip_runtime.h>

// StableContrastiveLoss on MI355X (gfx950).  B=4096, D=512, C=10, T=0.07.
// Round 5: R1's PROVEN 64x64-tile LDS sim kernel (45.5 us @ 4096 blocks,
// 66% occupancy) + upper-triangle symmetry (2080 blocks, half FLOPs, col-sum
// mirror on off-diag tiles). R3/R4 post-mortem: 528-block grids (2 blk/CU)
// are latency-exposed regardless of inner-loop structure -> keep many small
// blocks. No threadfence/ticket (suspected L2-writeback cost); finalize is a
// separate dispatch.
// ws: F_bf16 [4096*512] | cls [4096] | pos_sum [4096] | all_sum [4096]

#define B_ROWS 4096
#define D_DIM  512
#define C_CLS  10
#define NT     64                     // 4096/64 tiles per dim
#define NTILES (NT * (NT + 1) / 2)    // 2080 upper-triangle tiles
#define ASTRIDE 72  // 64+8 bf16 pad: 144B row stride breaks pow2 bank wrap

typedef __bf16 bf16x8 __attribute__((ext_vector_type(8)));
typedef float  f32x4  __attribute__((ext_vector_type(4)));

// ---------------- Kernel 1: normalize rows + class extract + zero accum ----
__global__ __launch_bounds__(256) void prep_kernel(
    const float* __restrict__ feats, const float* __restrict__ labels,
    __bf16* __restrict__ F, int* __restrict__ cls,
    float* __restrict__ pos_sum, float* __restrict__ all_sum) {
  const int w = threadIdx.x >> 6, lane = threadIdx.x & 63;
  const int row = blockIdx.x * 4 + w;   // one wave per row
  const float* fr = feats + (size_t)row * D_DIM;
  float4 v0 = ((const float4*)fr)[2 * lane];
  float4 v1 = ((const float4*)fr)[2 * lane + 1];
  float ss = v0.x*v0.x + v0.y*v0.y + v0.z*v0.z + v0.w*v0.w
           + v1.x*v1.x + v1.y*v1.y + v1.z*v1.z + v1.w*v1.w;
  #pragma unroll
  for (int m = 1; m < 64; m <<= 1) ss += __shfl_xor(ss, m, 64);
  float inv = 1.0f / sqrtf(ss);

  bf16x8 o;
  o[0] = (__bf16)(v0.x * inv); o[1] = (__bf16)(v0.y * inv);
  o[2] = (__bf16)(v0.z * inv); o[3] = (__bf16)(v0.w * inv);
  o[4] = (__bf16)(v1.x * inv); o[5] = (__bf16)(v1.y * inv);
  o[6] = (__bf16)(v1.z * inv); o[7] = (__bf16)(v1.w * inv);
  *(bf16x8*)(F + (size_t)row * D_DIM + 8 * lane) = o;

  float lv = (lane < C_CLS) ? labels[(size_t)row * C_CLS + lane] : 0.f;
  unsigned long long m = __ballot(lv > 0.5f);
  if (lane == 0) {
    cls[row] = (int)(__ffsll((long long)m) - 1);
    pos_sum[row] = 0.f;
    all_sum[row] = 0.f;
  }
}

// ------- Kernel 2: symmetric 64x64-tile sim + exp + row/col sums -----------
__global__ __launch_bounds__(256) void sim_kernel(
    const __bf16* __restrict__ F, const int* __restrict__ cls,
    float* __restrict__ pos_sum, float* __restrict__ all_sum) {
  __shared__ __align__(16) __bf16 Abuf[64][ASTRIDE];
  __shared__ __align__(16) __bf16 Bbuf[64][ASTRIDE];
  __shared__ int clsA[64], clsB[64];

  // triangular tile decode (block-uniform scalar loop, <=64 iters)
  int rem = blockIdx.x, bi = 0, rowlen = NT;
  while (rem >= rowlen) { rem -= rowlen; ++bi; --rowlen; }
  const int bj = bi + rem;
  const int i0 = bi * 64, j0 = bj * 64;
  const bool offdiag = (bi != bj);

  const int t = threadIdx.x;       // 256 threads = 4 waves
  const int w = t >> 6;
  const int lane = t & 63;
  const int q = lane >> 4;         // quad (k-group / acc-row selector)
  const int cl = lane & 15;        // fragment row/col index

  if (t < 64)       clsA[t]      = cls[i0 + t];
  else if (t < 128) clsB[t - 64] = cls[j0 + t - 64];

  f32x4 acc[4];
  #pragma unroll
  for (int c = 0; c < 4; ++c) acc[c] = (f32x4){0.f, 0.f, 0.f, 0.f};

  // staging: thread t -> row t/4, 16-col chunk (t%4)*16 (proven R1 layout)
  const int sr = t >> 2;
  const int sc = (t & 3) * 16;

  for (int k0 = 0; k0 < D_DIM; k0 += 64) {
    __syncthreads();  // protect LDS from previous iteration's readers
    {
      const uint4* ga = (const uint4*)(F + (size_t)(i0 + sr) * D_DIM + k0 + sc);
      const uint4* gb = (const uint4*)(F + (size_t)(j0 + sr) * D_DIM + k0 + sc);
      uint4 a0 = ga[0], a1 = ga[1];
      uint4 b0 = gb[0], b1 = gb[1];
      *(uint4*)&Abuf[sr][sc]     = a0;
      *(uint4*)&Abuf[sr][sc + 8] = a1;
      *(uint4*)&Bbuf[sr][sc]     = b0;
      *(uint4*)&Bbuf[sr][sc + 8] = b1;
    }
    __syncthreads();

    #pragma unroll
    for (int kk = 0; kk < 64; kk += 32) {
      bf16x8 af = *(const bf16x8*)&Abuf[16*w + cl][kk + q*8];
      #pragma unroll
      for (int c = 0; c < 4; ++c) {
        bf16x8 bfr = *(const bf16x8*)&Bbuf[16*c + cl][kk + q*8];
        acc[c] = __builtin_amdgcn_mfma_f32_16x16x32_bf16(af, bfr, acc[c], 0, 0, 0);
      }
    }
  }

  // Epilogue. D layout (m89/m91): col = lane&15, row = (lane>>4)*4 + reg.
  // Wave w owns rows 16w..16w+15 of the tile, all 64 cols.
  const float invT = 1.0f / 0.07f;
  float sum_all[4] = {0.f, 0.f, 0.f, 0.f};   // per acc-reg row partials
  float sum_pos[4] = {0.f, 0.f, 0.f, 0.f};
  float cs_all[4]  = {0.f, 0.f, 0.f, 0.f};   // per col-block partials (lane=col)
  float cs_pos[4]  = {0.f, 0.f, 0.f, 0.f};

  #pragma unroll
  for (int c = 0; c < 4; ++c) {
    const int jloc = 16*c + cl;
    const int gj = j0 + jloc;
    const int cj = clsB[jloc];
    #pragma unroll
    for (int r = 0; r < 4; ++r) {
      const int iloc = 16*w + q*4 + r;
      const int gi = i0 + iloc;
      float s = acc[c][r] * invT;
      s = fminf(fmaxf(s, -20.f), 20.f);
      const bool diag = (gi == gj);
      float e = diag ? 0.f : __expf(s);
      sum_all[r] += e;
      cs_all[c] += e;
      if (!diag && cj == clsA[iloc]) { sum_pos[r] += e; cs_pos[c] += e; }
    }
  }

  // row sums: reduce across the 16 lanes of each quad, 2 atomics per row
  #pragma unroll
  for (int r = 0; r < 4; ++r) {
    float sa = sum_all[r], sp = sum_pos[r];
    #pragma unroll
    for (int m = 1; m < 16; m <<= 1) {
      sa += __shfl_xor(sa, m, 64);
      sp += __shfl_xor(sp, m, 64);
    }
    if (cl == 0) {
      const int gi = i0 + 16*w + q*4 + r;
      atomicAdd(&all_sum[gi], sa);
      atomicAdd(&pos_sum[gi], sp);
    }
  }

  // col sums (symmetry mirror, off-diag tiles only): reduce across quads,
  // lane cl of quad 0 writes col 16c+cl
  if (offdiag) {
    #pragma unroll
    for (int c = 0; c < 4; ++c) {
      float sa = cs_all[c], sp = cs_pos[c];
      sa += __shfl_xor(sa, 16, 64); sa += __shfl_xor(sa, 32, 64);
      sp += __shfl_xor(sp, 16, 64); sp += __shfl_xor(sp, 32, 64);
      if (q == 0) {
        const int gj = j0 + 16*c + cl;
        atomicAdd(&all_sum[gj], sa);
        atomicAdd(&pos_sum[gj], sp);
      }
    }
  }
}

// ---------------- Kernel 3: final loss reduction ----------------
__global__ __launch_bounds__(256) void finalize_kernel(
    const float* __restrict__ pos_sum, const float* __restrict__ all_sum,
    float* __restrict__ out) {
  __shared__ float redT[4], redC[4];
  const int t = threadIdx.x;
  float total = 0.f, cnt = 0.f;
  for (int i = t; i < B_ROWS; i += 256) {
    float ps = pos_sum[i], as = all_sum[i];
    if (ps > 0.f) {   // row valid iff >=1 positive (exp > 0 always)
      total += -logf(ps / (as + 1e-8f) + 1e-8f);
      cnt += 1.f;
    }
  }
  #pragma unroll
  for (int m = 1; m < 64; m <<= 1) {
    total += __shfl_xor(total, m, 64);
    cnt   += __shfl_xor(cnt, m, 64);
  }
  if ((t & 63) == 0) { redT[t >> 6] = total; redC[t >> 6] = cnt; }
  __syncthreads();
  if (t == 0) {
    float T = 0.f, Cn = 0.f;
    #pragma unroll
    for (int i = 0; i < 4; ++i) { T += redT[i]; Cn += redC[i]; }
    out[0] = (Cn > 0.f) ? (T / Cn) : 0.f;
  }
}

extern "C" void kernel_launch(void* const* d_in, const int* in_sizes, int n_in,
                              void* d_out, int out_size, void* d_ws, size_t ws_size,
                              hipStream_t stream) {
  const float* features = (const float*)d_in[0];
  const float* labels   = (const float*)d_in[1];
  float* out = (float*)d_out;

  __bf16* F       = (__bf16*)d_ws;
  int*    cls     = (int*)((char*)d_ws + (size_t)B_ROWS * D_DIM * 2);
  float*  pos_sum = (float*)((char*)cls + B_ROWS * sizeof(int));
  float*  all_sum = pos_sum + B_ROWS;

  prep_kernel<<<B_ROWS / 4, 256, 0, stream>>>(features, labels, F, cls,
                                              pos_sum, all_sum);
  sim_kernel<<<NTILES, 256, 0, stream>>>(F, cls, pos_sum, all_sum);
  finalize_kernel<<<1, 256, 0, stream>>>(pos_sum, all_sum, out);
}